// Round 6
// baseline (206.530 us; speedup 1.0000x reference)
//
#include <hip/hip_runtime.h>
#include <hip/hip_bf16.h>
#include <stdint.h>

// Problem constants
#define M_TOK 2048   // B*S
#define N_OUT 4096   // OUT_F
#define K_IN  4096   // IN_F
#define GROUPSZ 128
#define NGRP  32

typedef __bf16 bf16_t;
typedef bf16_t bf16x4 __attribute__((ext_vector_type(4)));
typedef bf16_t bf16x8 __attribute__((ext_vector_type(8)));
typedef float  floatx4  __attribute__((ext_vector_type(4)));
typedef float  floatx16 __attribute__((ext_vector_type(16)));

__device__ __forceinline__ bf16_t f2bf(float f) { return (bf16_t)f; }

// ---------------- Kernel 1: fused conversion pass (one dispatch).
// Blocks [0, XCONV_BLOCKS): x fp32 -> bf16, 8 elems/thread (2x float4).
// Blocks [XCONV_BLOCKS, ...): w int32 * s_w -> bf16, 8 elems/thread (2x int4).
// w_q flat layout: [o][g][k'] = o*4096 + g*128 + k'  -> row-major (O, K) = B^T
// s_w flat layout: [g][o] = g*4096 + o
// Near its traffic floor (144 MB ~ 23 us); round-1..5 deltas show conversion
// was never the dominant non-GEMM cost (harness reset nodes are ~100 us fixed).
#define XCONV_BLOCKS (M_TOK * K_IN / 8 / 256)   // 4096
#define WCONV_BLOCKS (N_OUT * K_IN / 8 / 256)   // 8192

__global__ __launch_bounds__(256) void convert_kernel(
    const float* __restrict__ x, const int* __restrict__ wq,
    const float* __restrict__ sw, bf16_t* __restrict__ xb,
    bf16_t* __restrict__ wb) {
  int b = blockIdx.x;
  if (b < XCONV_BLOCKS) {
    size_t i = ((size_t)b * 256 + threadIdx.x) * 8;
    float4 a0 = *(const float4*)(x + i);
    float4 a1 = *(const float4*)(x + i + 4);
    bf16x8 o;
    o[0] = f2bf(a0.x); o[1] = f2bf(a0.y); o[2] = f2bf(a0.z); o[3] = f2bf(a0.w);
    o[4] = f2bf(a1.x); o[5] = f2bf(a1.y); o[6] = f2bf(a1.z); o[7] = f2bf(a1.w);
    *(bf16x8*)(xb + i) = o;
  } else {
    size_t t = (size_t)(b - XCONV_BLOCKS) * 256 + threadIdx.x; // 2M threads
    int o  = (int)(t >> 9);             // 512 chunks of 8 per K-row
    int kc = ((int)t & 511) << 3;       // 8 consecutive k (same group: 8|128)
    float s = sw[(kc >> 7) * N_OUT + o];
    const int* src = wq + (size_t)o * K_IN + kc;
    int4 a = *(const int4*)(src);
    int4 c = *(const int4*)(src + 4);
    bf16x8 ov;
    ov[0] = f2bf((float)a.x * s); ov[1] = f2bf((float)a.y * s);
    ov[2] = f2bf((float)a.z * s); ov[3] = f2bf((float)a.w * s);
    ov[4] = f2bf((float)c.x * s); ov[5] = f2bf((float)c.y * s);
    ov[6] = f2bf((float)c.z * s); ov[7] = f2bf((float)c.w * s);
    *(bf16x8*)(wb + (size_t)o * K_IN + kc) = ov;
  }
}

// ---------------- Kernel 2: GEMM C = A(2048xK) * Bt(4096xK)^T + bias
// 128x128 tile, BK=128 (32 K-iters), 8 waves (4x2, 512 threads), wave-tile
// 32x64 = 1x2 blocks of *mfma_f32_32x32x16_bf16* (15% faster pipe than 16x16,
// half the MFMA instruction count, same LDS bytes/FLOP).
// global_load_lds width=16 staging, XOR-swizzled LDS chunk layout
// (conflict-free reads: lanes l/l+16 alias 2-way which is free; 16 XOR chunk
// values cover all bank groups evenly).
// A-operand layout: A[m=lane&31][k=(lane>>5)*8 + j] (analog of the verified
// 16x16x32 mapping). C/D layout (m74/m101-verified):
//   col = lane&31, row = (reg&3) + 8*(reg>>2) + 4*(lane>>5).
#define BM 128
#define BN 128
#define BK 128

__global__ __launch_bounds__(512) void gemm_bias_kernel(
    const bf16_t* __restrict__ A, const bf16_t* __restrict__ Bt,
    const float* __restrict__ bias, float* __restrict__ C) {
  __shared__ bf16_t As[BM * BK];   // 32 KB
  __shared__ bf16_t Bs[BN * BK];   // 32 KB

  const int tid  = threadIdx.x;
  const int lane = tid & 63;
  const int wave = tid >> 6;       // 0..7
  const int bm = blockIdx.y;
  const int bn = blockIdx.x;
  const int wm = wave >> 1;        // 0..3 -> 32-row slab
  const int wn = wave & 1;         // 0..1 -> 64-col slab

  const int rowA0 = bm * BM;
  const int rowB0 = bn * BN;

  floatx16 acc[2];
  acc[0] = (floatx16)0.0f;
  acc[1] = (floatx16)0.0f;

  const int l31  = lane & 31;
  const int half = lane >> 5;      // 0..1

  for (int k0 = 0; k0 < K_IN; k0 += BK) {
    __syncthreads();   // previous compute done before LDS overwrite
    // Stage A-tile and B-tile: 2048 chunks of 16 B each per matrix,
    // 4 per thread per matrix. LDS dest is wave-uniform base + lane*16
    // (global_load_lds constraint). Global source column is XOR-swizzled
    // (16 chunks/row, mask 15) so LDS fragment reads are conflict-free.
#pragma unroll
    for (int i = 0; i < 4; ++i) {
      int chunk = i * 512 + tid;            // wave-contiguous, 0..2047
      int row = chunk >> 4;                 // tile row 0..127
      int csw = (chunk & 15) ^ (row & 15);  // swizzled k-chunk 0..15
      int col = csw << 3;                   // k elem offset 0..120
      const bf16_t* srcA = A  + (size_t)(rowA0 + row) * K_IN + k0 + col;
      const bf16_t* srcB = Bt + (size_t)(rowB0 + row) * K_IN + k0 + col;
      __builtin_amdgcn_global_load_lds(
          (const __attribute__((address_space(1))) void*)srcA,
          (__attribute__((address_space(3))) void*)(As + (size_t)(i * 512 + wave * 64) * 8),
          16, 0, 0);
      __builtin_amdgcn_global_load_lds(
          (const __attribute__((address_space(1))) void*)srcB,
          (__attribute__((address_space(3))) void*)(Bs + (size_t)(i * 512 + wave * 64) * 8),
          16, 0, 0);
    }
    __syncthreads();   // compiler emits vmcnt(0) drain before barrier

#pragma unroll
    for (int kk = 0; kk < BK; kk += 16) {
      const int kc = (kk >> 3) + half;      // k-chunk index 0..15
      bf16x8 af, bfr[2];
      {
        int r = wm * 32 + l31;              // m index
        af = *(const bf16x8*)(As + (size_t)(r * 16 + (kc ^ (r & 15))) * 8);
      }
#pragma unroll
      for (int j = 0; j < 2; ++j) {
        int r = wn * 64 + j * 32 + l31;     // n index
        bfr[j] = *(const bf16x8*)(Bs + (size_t)(r * 16 + (kc ^ (r & 15))) * 8);
      }
#pragma unroll
      for (int j = 0; j < 2; ++j)
        acc[j] = __builtin_amdgcn_mfma_f32_32x32x16_bf16(af, bfr[j], acc[j], 0, 0, 0);
    }
  }

  // Epilogue: col = lane&31 (n), row = (reg&3) + 8*(reg>>2) + 4*half (m).
  // Plain stores (NT regressed WRITE_SIZE 33->44 MB in round 5: partial-line
  // NT defeats L2 write-combining of the two half-lines per 128B line).
#pragma unroll
  for (int j = 0; j < 2; ++j) {
    int col = rowB0 + wn * 64 + j * 32 + l31;
    float bv = bias[col];
#pragma unroll
    for (int reg = 0; reg < 16; ++reg) {
      int row = rowA0 + wm * 32 + (reg & 3) + 8 * (reg >> 2) + 4 * half;
      C[(size_t)row * N_OUT + col] = acc[j][reg] + bv;
    }
  }
}

extern "C" void kernel_launch(void* const* d_in, const int* in_sizes, int n_in,
                              void* d_out, int out_size, void* d_ws, size_t ws_size,
                              hipStream_t stream) {
  const float* x    = (const float*)d_in[0];
  const int*   wq   = (const int*)d_in[1];     // integer input -> int32 per harness
  const float* sw   = (const float*)d_in[2];
  const float* bias = (const float*)d_in[3];
  float* out = (float*)d_out;

  bf16_t* xb = (bf16_t*)d_ws;                                     // 16 MB
  bf16_t* wb = (bf16_t*)((char*)d_ws + (size_t)M_TOK * K_IN * 2); // 32 MB

  {
    int nblocks = XCONV_BLOCKS + WCONV_BLOCKS;  // 12288
    convert_kernel<<<nblocks, 256, 0, stream>>>(x, wq, sw, xb, wb);
  }
  {
    dim3 grid(N_OUT / BN, M_TOK / BM);          // (32, 16) = 512 blocks
    gemm_bias_kernel<<<grid, 512, 0, stream>>>(xb, wb, bias, out);
  }
}

// Round 7
// 193.357 us; speedup vs baseline: 1.0681x; 1.0681x over previous
//
#include <hip/hip_runtime.h>
#include <hip/hip_bf16.h>
#include <stdint.h>

// Problem constants
#define M_TOK 2048   // B*S
#define N_OUT 4096   // OUT_F
#define K_IN  4096   // IN_F
#define GROUPSZ 128
#define NGRP  32

typedef __bf16 bf16_t;
typedef bf16_t bf16x4 __attribute__((ext_vector_type(4)));
typedef bf16_t bf16x8 __attribute__((ext_vector_type(8)));
typedef float  floatx4 __attribute__((ext_vector_type(4)));

__device__ __forceinline__ bf16_t f2bf(float f) { return (bf16_t)f; }

// ---------------- Kernel 1: fused conversion pass (one dispatch).
// Blocks [0, XCONV_BLOCKS): x fp32 -> bf16, 8 elems/thread (2x float4).
// Blocks [XCONV_BLOCKS, ...): w int32 * s_w -> bf16, 8 elems/thread (2x int4).
// w_q flat layout: [o][g][k'] = o*4096 + g*128 + k'  -> row-major (O, K) = B^T
// s_w flat layout: [g][o] = g*4096 + o
// Near its traffic floor (~148 MB ~ 24 us at 6.3 TB/s).
#define XCONV_BLOCKS (M_TOK * K_IN / 8 / 256)   // 4096
#define WCONV_BLOCKS (N_OUT * K_IN / 8 / 256)   // 8192

__global__ __launch_bounds__(256) void convert_kernel(
    const float* __restrict__ x, const int* __restrict__ wq,
    const float* __restrict__ sw, bf16_t* __restrict__ xb,
    bf16_t* __restrict__ wb) {
  int b = blockIdx.x;
  if (b < XCONV_BLOCKS) {
    size_t i = ((size_t)b * 256 + threadIdx.x) * 8;
    float4 a0 = *(const float4*)(x + i);
    float4 a1 = *(const float4*)(x + i + 4);
    bf16x8 o;
    o[0] = f2bf(a0.x); o[1] = f2bf(a0.y); o[2] = f2bf(a0.z); o[3] = f2bf(a0.w);
    o[4] = f2bf(a1.x); o[5] = f2bf(a1.y); o[6] = f2bf(a1.z); o[7] = f2bf(a1.w);
    *(bf16x8*)(xb + i) = o;
  } else {
    size_t t = (size_t)(b - XCONV_BLOCKS) * 256 + threadIdx.x; // 2M threads
    int o  = (int)(t >> 9);             // 512 chunks of 8 per K-row
    int kc = ((int)t & 511) << 3;       // 8 consecutive k (same group: 8|128)
    float s = sw[(kc >> 7) * N_OUT + o];
    const int* src = wq + (size_t)o * K_IN + kc;
    int4 a = *(const int4*)(src);
    int4 c = *(const int4*)(src + 4);
    bf16x8 ov;
    ov[0] = f2bf((float)a.x * s); ov[1] = f2bf((float)a.y * s);
    ov[2] = f2bf((float)a.z * s); ov[3] = f2bf((float)a.w * s);
    ov[4] = f2bf((float)c.x * s); ov[5] = f2bf((float)c.y * s);
    ov[6] = f2bf((float)c.z * s); ov[7] = f2bf((float)c.w * s);
    *(bf16x8*)(wb + (size_t)o * K_IN + kc) = ov;
  }
}

// ---------------- Kernel 2: GEMM C = A(2048xK) * Bt(4096xK)^T + bias
// Best-known config (recombination of verified wins):
//  - 128x128 tile, BK=128 (32 K-iters; R5: barrier amortization, 73.4->69.1)
//  - 8 waves (4x2, 512 threads), wave-tile 32x64, 2x4 frags of 16x16x32 bf16
//    (R4: 4 waves/SIMD, the occupancy win; R6 showed 32x32x16 regresses —
//    only 2 accumulator chains can't cover MFMA latency)
//  - global_load_lds width=16 staging, XOR-swizzled chunk layout
//    (R2: conflict-free LDS reads, SQ_LDS_BANK_CONFLICT = 0)
//  - plain epilogue stores (R5/R6: NT partial-line stores defeat L2
//    write-combining, WRITE_SIZE 33->44 MB; plain gives exactly 32 MB)
#define BM 128
#define BN 128
#define BK 128

__global__ __launch_bounds__(512) void gemm_bias_kernel(
    const bf16_t* __restrict__ A, const bf16_t* __restrict__ Bt,
    const float* __restrict__ bias, float* __restrict__ C) {
  __shared__ bf16_t As[BM * BK];   // 32 KB
  __shared__ bf16_t Bs[BN * BK];   // 32 KB

  const int tid  = threadIdx.x;
  const int lane = tid & 63;
  const int wave = tid >> 6;       // 0..7
  const int bm = blockIdx.y;
  const int bn = blockIdx.x;
  const int wm = wave >> 1;        // 0..3 -> 32-row slab
  const int wn = wave & 1;         // 0..1 -> 64-col slab

  const int rowA0 = bm * BM;
  const int rowB0 = bn * BN;

  floatx4 acc[2][4];
#pragma unroll
  for (int i = 0; i < 2; ++i)
#pragma unroll
    for (int j = 0; j < 4; ++j) acc[i][j] = (floatx4)0.0f;

  const int quad = lane >> 4;      // 0..3
  const int l16  = lane & 15;

  for (int k0 = 0; k0 < K_IN; k0 += BK) {
    __syncthreads();   // previous compute done before LDS overwrite
    // Stage A-tile and B-tile: 2048 chunks of 16 B each per matrix,
    // 4 per thread per matrix. LDS dest is wave-uniform base + lane*16
    // (global_load_lds constraint). Global source column is XOR-swizzled
    // (16 chunks/row, mask 15) so LDS fragment reads are conflict-free.
#pragma unroll
    for (int i = 0; i < 4; ++i) {
      int chunk = i * 512 + tid;            // wave-contiguous, 0..2047
      int row = chunk >> 4;                 // tile row 0..127
      int csw = (chunk & 15) ^ (row & 15);  // swizzled k-chunk 0..15
      int col = csw << 3;                   // k elem offset 0..120
      const bf16_t* srcA = A  + (size_t)(rowA0 + row) * K_IN + k0 + col;
      const bf16_t* srcB = Bt + (size_t)(rowB0 + row) * K_IN + k0 + col;
      __builtin_amdgcn_global_load_lds(
          (const __attribute__((address_space(1))) void*)srcA,
          (__attribute__((address_space(3))) void*)(As + (size_t)(i * 512 + wave * 64) * 8),
          16, 0, 0);
      __builtin_amdgcn_global_load_lds(
          (const __attribute__((address_space(1))) void*)srcB,
          (__attribute__((address_space(3))) void*)(Bs + (size_t)(i * 512 + wave * 64) * 8),
          16, 0, 0);
    }
    __syncthreads();   // compiler emits vmcnt(0) drain before barrier

#pragma unroll
    for (int kk = 0; kk < BK; kk += 32) {
      bf16x8 af[2], bfr[4];
      const int kc16 = (kk >> 3) + quad;    // k-chunk index 0..15
#pragma unroll
      for (int i = 0; i < 2; ++i) {
        int r = wm * 32 + i * 16 + l16;     // m index
        af[i] = *(const bf16x8*)(As + (size_t)(r * 16 + (kc16 ^ (r & 15))) * 8);
      }
#pragma unroll
      for (int j = 0; j < 4; ++j) {
        int r = wn * 64 + j * 16 + l16;     // n index
        bfr[j] = *(const bf16x8*)(Bs + (size_t)(r * 16 + (kc16 ^ (r & 15))) * 8);
      }
#pragma unroll
      for (int i = 0; i < 2; ++i)
#pragma unroll
        for (int j = 0; j < 4; ++j)
          acc[i][j] = __builtin_amdgcn_mfma_f32_16x16x32_bf16(af[i], bfr[j], acc[i][j], 0, 0, 0);
    }
  }

  // Epilogue: C/D layout col = lane&15 (n), row = quad*4 + reg (m). Fused bias.
#pragma unroll
  for (int j = 0; j < 4; ++j) {
    int col = rowB0 + wn * 64 + j * 16 + l16;
    float bv = bias[col];
#pragma unroll
    for (int i = 0; i < 2; ++i) {
      int rowbase = rowA0 + wm * 32 + i * 16 + quad * 4;
#pragma unroll
      for (int r = 0; r < 4; ++r) {
        C[(size_t)(rowbase + r) * N_OUT + col] = acc[i][j][r] + bv;
      }
    }
  }
}

extern "C" void kernel_launch(void* const* d_in, const int* in_sizes, int n_in,
                              void* d_out, int out_size, void* d_ws, size_t ws_size,
                              hipStream_t stream) {
  const float* x    = (const float*)d_in[0];
  const int*   wq   = (const int*)d_in[1];     // integer input -> int32 per harness
  const float* sw   = (const float*)d_in[2];
  const float* bias = (const float*)d_in[3];
  float* out = (float*)d_out;

  bf16_t* xb = (bf16_t*)d_ws;                                     // 16 MB
  bf16_t* wb = (bf16_t*)((char*)d_ws + (size_t)M_TOK * K_IN * 2); // 32 MB

  {
    int nblocks = XCONV_BLOCKS + WCONV_BLOCKS;  // 12288
    convert_kernel<<<nblocks, 256, 0, stream>>>(x, wq, sw, xb, wb);
  }
  {
    dim3 grid(N_OUT / BN, M_TOK / BM);          // (32, 16) = 512 blocks
    gemm_bias_kernel<<<grid, 512, 0, stream>>>(xb, wb, bias, out);
  }
}

// Round 8
// 170.462 us; speedup vs baseline: 1.2116x; 1.1343x over previous
//
#include <hip/hip_runtime.h>
#include <hip/hip_bf16.h>
#include <stdint.h>

// Problem constants
#define M_TOK 2048   // B*S
#define N_OUT 4096   // OUT_F
#define K_IN  4096   // IN_F
#define GROUPSZ 128
#define NGRP  32

typedef signed char i8;
typedef int    intx4  __attribute__((ext_vector_type(4)));
typedef float  floatx4 __attribute__((ext_vector_type(4)));

// ---------------- Kernel 1: fused quantization pass (one dispatch).
// Blocks [0, 2048): quantize one row of x to int8 with per-row scale
//   s_x[n] = rowmax/127 (symmetric). w stays EXACT (ints in [-7,7]).
// Blocks [2048, 2048+4096): narrow w int32 -> int8 (exact), 16 elems/thread.
#define XQ_BLOCKS (M_TOK)                       // 2048, 256 thr = 1 row
#define WQ_BLOCKS (N_OUT * K_IN / 16 / 256)     // 4096

__global__ __launch_bounds__(256) void quant_kernel(
    const float* __restrict__ x, const int* __restrict__ wq,
    i8* __restrict__ xq, i8* __restrict__ wq8, float* __restrict__ sx) {
  __shared__ float red[4];
  int b = blockIdx.x;
  int tid = threadIdx.x;
  if (b < XQ_BLOCKS) {
    const float* xr = x + (size_t)b * K_IN;
    int e0 = tid * 16;
    float4 v0 = *(const float4*)(xr + e0);
    float4 v1 = *(const float4*)(xr + e0 + 4);
    float4 v2 = *(const float4*)(xr + e0 + 8);
    float4 v3 = *(const float4*)(xr + e0 + 12);
    float m = fabsf(v0.x);
    m = fmaxf(m, fabsf(v0.y)); m = fmaxf(m, fabsf(v0.z)); m = fmaxf(m, fabsf(v0.w));
    m = fmaxf(m, fabsf(v1.x)); m = fmaxf(m, fabsf(v1.y)); m = fmaxf(m, fabsf(v1.z)); m = fmaxf(m, fabsf(v1.w));
    m = fmaxf(m, fabsf(v2.x)); m = fmaxf(m, fabsf(v2.y)); m = fmaxf(m, fabsf(v2.z)); m = fmaxf(m, fabsf(v2.w));
    m = fmaxf(m, fabsf(v3.x)); m = fmaxf(m, fabsf(v3.y)); m = fmaxf(m, fabsf(v3.z)); m = fmaxf(m, fabsf(v3.w));
#pragma unroll
    for (int off = 32; off > 0; off >>= 1)
      m = fmaxf(m, __shfl_xor(m, off, 64));
    int lane = tid & 63, wv = tid >> 6;
    if (lane == 0) red[wv] = m;
    __syncthreads();
    m = fmaxf(fmaxf(red[0], red[1]), fmaxf(red[2], red[3]));
    float inv = (m > 0.f) ? 127.f / m : 0.f;
    union { i8 q[16]; int4 v; } u;
    u.q[0]  = (i8)(int)rintf(v0.x * inv); u.q[1]  = (i8)(int)rintf(v0.y * inv);
    u.q[2]  = (i8)(int)rintf(v0.z * inv); u.q[3]  = (i8)(int)rintf(v0.w * inv);
    u.q[4]  = (i8)(int)rintf(v1.x * inv); u.q[5]  = (i8)(int)rintf(v1.y * inv);
    u.q[6]  = (i8)(int)rintf(v1.z * inv); u.q[7]  = (i8)(int)rintf(v1.w * inv);
    u.q[8]  = (i8)(int)rintf(v2.x * inv); u.q[9]  = (i8)(int)rintf(v2.y * inv);
    u.q[10] = (i8)(int)rintf(v2.z * inv); u.q[11] = (i8)(int)rintf(v2.w * inv);
    u.q[12] = (i8)(int)rintf(v3.x * inv); u.q[13] = (i8)(int)rintf(v3.y * inv);
    u.q[14] = (i8)(int)rintf(v3.z * inv); u.q[15] = (i8)(int)rintf(v3.w * inv);
    *(int4*)(xq + (size_t)b * K_IN + e0) = u.v;
    if (tid == 0) sx[b] = m * (1.f / 127.f);
  } else {
    size_t t = (size_t)(b - XQ_BLOCKS) * 256 + tid;   // 1M threads
    size_t base = t * 16;
    const int* src = wq + base;
    int4 a0 = *(const int4*)(src);
    int4 a1 = *(const int4*)(src + 4);
    int4 a2 = *(const int4*)(src + 8);
    int4 a3 = *(const int4*)(src + 12);
    union { i8 q[16]; int4 v; } u;
    u.q[0]  = (i8)a0.x; u.q[1]  = (i8)a0.y; u.q[2]  = (i8)a0.z; u.q[3]  = (i8)a0.w;
    u.q[4]  = (i8)a1.x; u.q[5]  = (i8)a1.y; u.q[6]  = (i8)a1.z; u.q[7]  = (i8)a1.w;
    u.q[8]  = (i8)a2.x; u.q[9]  = (i8)a2.y; u.q[10] = (i8)a2.z; u.q[11] = (i8)a2.w;
    u.q[12] = (i8)a3.x; u.q[13] = (i8)a3.y; u.q[14] = (i8)a3.z; u.q[15] = (i8)a3.w;
    *(int4*)(wq8 + base) = u.v;
  }
}

// ---------------- Kernel 2: int8 GEMM with per-group fp32 rescale + bias.
// y[n,o] = s_x[n] * sum_g( s_w[g,o] * dot_i32(xq[n,g,:], w[o,g,:]) ) + bias[o]
// Structure (all pieces verified in R2/R4/R5):
//  - 128x128 tile, BK=128 == GROUPSZ: one K-tile == one quant group, so the
//    int32 MFMA accumulator is exact per group; rescale by s_w[g,col] per tile
//    (64 VALU/wave/tile, overlaps 17%-busy VALU pipe); s_x per row at epilogue.
//  - 8 waves (4x2, 512 threads), wave-tile 32x64, 2x4 frags of
//    mfma_i32_16x16x64_i8 (2x bf16 rate; A/B = 16 consecutive int8 along k:
//    m=lane&15, k=quad*16+j — exact analog of verified bf16 16x16x32 map).
//  - global_load_lds width=16 staging (half the loads of bf16), XOR-swizzled
//    16B-chunk layout: 8 chunks/row, csw = c ^ (row&7) -> per-quad chunk
//    columns fully spread, conflict-free (R2-verified pattern).
#define BM 128
#define BN 128
#define BK 128

__global__ __launch_bounds__(512) void gemm_i8_kernel(
    const i8* __restrict__ Aq, const i8* __restrict__ Bq,
    const float* __restrict__ sx, const float* __restrict__ sw,
    const float* __restrict__ bias, float* __restrict__ C) {
  __shared__ i8 As[BM * BK];            // 16 KB
  __shared__ i8 Bs[BN * BK];            // 16 KB
  __shared__ float sws[NGRP * BN];      // 16 KB: s_w[g][rowB0 + c]
  __shared__ float sxs[BM];             // 512 B: s_x[rowA0 + r]

  const int tid  = threadIdx.x;
  const int lane = tid & 63;
  const int wave = tid >> 6;       // 0..7
  const int bm = blockIdx.y;
  const int bn = blockIdx.x;
  const int wm = wave >> 1;        // 0..3 -> 32-row slab
  const int wn = wave & 1;         // 0..1 -> 64-col slab

  const int rowA0 = bm * BM;
  const int rowB0 = bn * BN;

  // One-time LDS staging of scales (ordered before use by the loop barriers).
  {
    int g = tid >> 4, c0 = (tid & 15) * 8;
    const float* src = sw + (size_t)g * N_OUT + rowB0 + c0;
    *(float4*)(sws + g * BN + c0)     = *(const float4*)(src);
    *(float4*)(sws + g * BN + c0 + 4) = *(const float4*)(src + 4);
    if (tid < BM) sxs[tid] = sx[rowA0 + tid];
  }

  floatx4 master[2][4];
#pragma unroll
  for (int i = 0; i < 2; ++i)
#pragma unroll
    for (int j = 0; j < 4; ++j) master[i][j] = (floatx4)0.0f;

  const int quad = lane >> 4;      // 0..3
  const int l16  = lane & 15;

  for (int k0 = 0, g = 0; k0 < K_IN; k0 += BK, ++g) {
    __syncthreads();   // previous compute done before LDS overwrite
    // Stage A/B tiles: 1024 chunks of 16 B per matrix, 2 per thread each.
    // LDS dest is wave-uniform base + lane*16 (global_load_lds constraint);
    // global source chunk-column XOR-swizzled for conflict-free reads.
#pragma unroll
    for (int i = 0; i < 2; ++i) {
      int chunk = i * 512 + tid;            // wave-contiguous, 0..1023
      int row = chunk >> 3;                 // tile row 0..127
      int csw = (chunk & 7) ^ (row & 7);    // swizzled 16B-chunk 0..7
      int col = csw << 4;                   // int8 elem offset 0..112
      const i8* srcA = Aq + (size_t)(rowA0 + row) * K_IN + k0 + col;
      const i8* srcB = Bq + (size_t)(rowB0 + row) * K_IN + k0 + col;
      __builtin_amdgcn_global_load_lds(
          (const __attribute__((address_space(1))) void*)srcA,
          (__attribute__((address_space(3))) void*)(As + (size_t)(i * 512 + wave * 64) * 16),
          16, 0, 0);
      __builtin_amdgcn_global_load_lds(
          (const __attribute__((address_space(1))) void*)srcB,
          (__attribute__((address_space(3))) void*)(Bs + (size_t)(i * 512 + wave * 64) * 16),
          16, 0, 0);
    }
    __syncthreads();   // vmcnt(0) drain before barrier

    intx4 acci[2][4];
#pragma unroll
    for (int s = 0; s < 2; ++s) {
      const int kc = s * 4 + quad;          // 16B-chunk index 0..7
      intx4 av[2], bv[4];
#pragma unroll
      for (int i = 0; i < 2; ++i) {
        int r = wm * 32 + i * 16 + l16;     // m index
        av[i] = *(const intx4*)(As + (size_t)(r * 8 + (kc ^ (r & 7))) * 16);
      }
#pragma unroll
      for (int j = 0; j < 4; ++j) {
        int r = wn * 64 + j * 16 + l16;     // n index
        bv[j] = *(const intx4*)(Bs + (size_t)(r * 8 + (kc ^ (r & 7))) * 16);
      }
#pragma unroll
      for (int i = 0; i < 2; ++i)
#pragma unroll
        for (int j = 0; j < 4; ++j) {
          intx4 c0 = (s == 0) ? (intx4)0 : acci[i][j];
          acci[i][j] = __builtin_amdgcn_mfma_i32_16x16x64_i8(av[i], bv[j], c0, 0, 0, 0);
        }
    }

    // Per-group rescale: master += f32(acc_i32) * s_w[g, col]
    float swv[4];
#pragma unroll
    for (int j = 0; j < 4; ++j)
      swv[j] = sws[g * BN + wn * 64 + j * 16 + l16];
#pragma unroll
    for (int i = 0; i < 2; ++i)
#pragma unroll
      for (int j = 0; j < 4; ++j)
#pragma unroll
        for (int r = 0; r < 4; ++r)
          master[i][j][r] += (float)acci[i][j][r] * swv[j];
  }

  // Epilogue: C/D layout col = lane&15 (n), row = quad*4 + reg (m).
  // y = master * s_x[row] + bias[col]. Plain stores (R6/R7: ideal WRITE_SIZE).
#pragma unroll
  for (int j = 0; j < 4; ++j) {
    int col = rowB0 + wn * 64 + j * 16 + l16;
    float bv = bias[col];
#pragma unroll
    for (int i = 0; i < 2; ++i) {
      int rloc = wm * 32 + i * 16 + quad * 4;
#pragma unroll
      for (int r = 0; r < 4; ++r) {
        C[(size_t)(rowA0 + rloc + r) * N_OUT + col] =
            master[i][j][r] * sxs[rloc + r] + bv;
      }
    }
  }
}

extern "C" void kernel_launch(void* const* d_in, const int* in_sizes, int n_in,
                              void* d_out, int out_size, void* d_ws, size_t ws_size,
                              hipStream_t stream) {
  const float* x    = (const float*)d_in[0];
  const int*   wq   = (const int*)d_in[1];     // integer input -> int32 per harness
  const float* sw   = (const float*)d_in[2];
  const float* bias = (const float*)d_in[3];
  float* out = (float*)d_out;

  i8*    xq  = (i8*)d_ws;                                          // 8 MB
  i8*    wq8 = (i8*)((char*)d_ws + (size_t)M_TOK * K_IN);          // 16 MB
  float* sx  = (float*)((char*)d_ws + (size_t)M_TOK * K_IN
                                     + (size_t)N_OUT * K_IN);      // 8 KB

  {
    int nblocks = XQ_BLOCKS + WQ_BLOCKS;        // 6144
    quant_kernel<<<nblocks, 256, 0, stream>>>(x, wq, xq, wq8, sx);
  }
  {
    dim3 grid(N_OUT / BN, M_TOK / BM);          // (32, 16) = 512 blocks
    gemm_i8_kernel<<<grid, 512, 0, stream>>>(xq, wq8, sx, sw, bias, out);
  }
}